// Round 1
// baseline (287.468 us; speedup 1.0000x reference)
//
#include <hip/hip_runtime.h>

#define B_TOTAL 2000000

// POLLU RHS: 25 fluxes, 20 species, stoichiometry hard-coded.
// conc: [20, B] species-major (coalesced reads, one thread per column b)
// out:  [B, 20] column-major-per-b (5 float4 stores per thread, 16B aligned)
__global__ __launch_bounds__(256) void pollu_kernel(
    const float* __restrict__ conc,
    const float* __restrict__ k,
    float* __restrict__ out)
{
    __shared__ float sk[25];
    if (threadIdx.x < 25) sk[threadIdx.x] = k[threadIdx.x];
    __syncthreads();

    const int b = blockIdx.x * blockDim.x + threadIdx.x;
    if (b >= B_TOTAL) return;

    const size_t B = (size_t)B_TOTAL;
    float c[20];
#pragma unroll
    for (int s = 0; s < 20; ++s) c[s] = conc[(size_t)s * B + (size_t)b];

    // flux r = k[r] * C[a_r] * C[b_r]  (index 20 == constant 1.0 row)
    const float f1  = sk[0]  * c[0];
    const float f2  = sk[1]  * c[1]  * c[3];
    const float f3  = sk[2]  * c[4]  * c[1];
    const float f4  = sk[3]  * c[6];
    const float f5  = sk[4]  * c[6];
    const float f6  = sk[5]  * c[6]  * c[5];
    const float f7  = sk[6]  * c[8];
    const float f8  = sk[7]  * c[8]  * c[5];
    const float f9  = sk[8]  * c[10] * c[1];
    const float f10 = sk[9]  * c[10] * c[0];
    const float f11 = sk[10] * c[12];
    const float f12 = sk[11] * c[9]  * c[1];
    const float f13 = sk[12] * c[13];
    const float f14 = sk[13] * c[0]  * c[5];
    const float f15 = sk[14] * c[2];
    const float f16 = sk[15] * c[3];
    const float f17 = sk[16] * c[3];
    const float f18 = sk[17] * c[15];
    const float f19 = sk[18] * c[15];
    const float f20 = sk[19] * c[16] * c[5];
    const float f21 = sk[20] * c[18];
    const float f22 = sk[21] * c[18];
    const float f23 = sk[22] * c[0]  * c[3];
    const float f24 = sk[23] * c[18] * c[0];
    const float f25 = sk[24] * c[19];

    // dy[s] = sum_r S[s][r] * flux[r], transcribed from the stoichiometry
    const float dy0  = -f1 - f10 - f14 - f23 - f24 + f2 + f3 + f9 + f11 + f12 + f22 + f25;
    const float dy1  = -f2 - f3 - f9 - f12 + f1 + f21;
    const float dy2  = -f15 + f1 + f17 + f19 + f22;
    const float dy3  = -f2 - f16 - f17 - f23 + f15;
    const float dy4  = -f3 + 2.0f * f4 + f6 + f7 + f13 + f20;
    const float dy5  = -f6 - f8 - f14 - f20 + f3 + 2.0f * f18;
    const float dy6  = -f4 - f5 - f6 + f13;
    const float dy7  =  f4 + f5 + f6 + f7;
    const float dy8  = -f7 - f8;
    const float dy9  = -f12 + f7 + f9;
    const float dy10 = -f9 - f10 + f8 + f11;
    const float dy11 =  f9;
    const float dy12 = -f11 + f10;
    const float dy13 = -f13 + f12;
    const float dy14 =  f14;
    const float dy15 = -f18 - f19 + f16;
    const float dy16 = -f20;
    const float dy17 =  f20;
    const float dy18 = -f21 - f22 - f24 + f23 + f25;
    const float dy19 = -f25 + f24;

    // out + b*20 floats = b*80 bytes -> 16B aligned, 5x float4
    float4* o = (float4*)(out + (size_t)b * 20u);
    o[0] = make_float4(dy0,  dy1,  dy2,  dy3);
    o[1] = make_float4(dy4,  dy5,  dy6,  dy7);
    o[2] = make_float4(dy8,  dy9,  dy10, dy11);
    o[3] = make_float4(dy12, dy13, dy14, dy15);
    o[4] = make_float4(dy16, dy17, dy18, dy19);
}

extern "C" void kernel_launch(void* const* d_in, const int* in_sizes, int n_in,
                              void* d_out, int out_size, void* d_ws, size_t ws_size,
                              hipStream_t stream) {
    // d_in[0] = t (unused), d_in[1] = conc_in [20, B], d_in[2] = k [25]
    const float* conc = (const float*)d_in[1];
    const float* k    = (const float*)d_in[2];
    float* out        = (float*)d_out;

    const int block = 256;
    const int grid  = (B_TOTAL + block - 1) / block;
    pollu_kernel<<<grid, block, 0, stream>>>(conc, k, out);
}

// Round 2
// 273.324 us; speedup vs baseline: 1.0517x; 1.0517x over previous
//
#include <hip/hip_runtime.h>

#define B_TOTAL 2000000
#define PAD 21  // 21 coprime with 32 banks -> conflict-free LDS writes

// POLLU RHS: 25 fluxes, 20 species, stoichiometry hard-coded.
// conc: [20, B] species-major (coalesced dword reads, one thread per column b)
// out:  [B, 20] -> staged through LDS so global stores are dense float4 sweeps
__global__ __launch_bounds__(256) void pollu_kernel(
    const float* __restrict__ conc,
    const float* __restrict__ k,
    float* __restrict__ out)
{
    __shared__ float sk[25];
    __shared__ float lds[256 * PAD];  // 21504 B

    if (threadIdx.x < 25) sk[threadIdx.x] = k[threadIdx.x];
    __syncthreads();

    const int t = threadIdx.x;
    const int blockStart = blockIdx.x * 256;
    const int b = blockStart + t;
    const int nvalid = min(256, B_TOTAL - blockStart);

    if (b < B_TOTAL) {
        const size_t B = (size_t)B_TOTAL;
        float c[20];
#pragma unroll
        for (int s = 0; s < 20; ++s) c[s] = conc[(size_t)s * B + (size_t)b];

        // flux r = k[r] * C[a_r] * C[b_r]  (index 20 == constant 1.0 row)
        const float f1  = sk[0]  * c[0];
        const float f2  = sk[1]  * c[1]  * c[3];
        const float f3  = sk[2]  * c[4]  * c[1];
        const float f4  = sk[3]  * c[6];
        const float f5  = sk[4]  * c[6];
        const float f6  = sk[5]  * c[6]  * c[5];
        const float f7  = sk[6]  * c[8];
        const float f8  = sk[7]  * c[8]  * c[5];
        const float f9  = sk[8]  * c[10] * c[1];
        const float f10 = sk[9]  * c[10] * c[0];
        const float f11 = sk[10] * c[12];
        const float f12 = sk[11] * c[9]  * c[1];
        const float f13 = sk[12] * c[13];
        const float f14 = sk[13] * c[0]  * c[5];
        const float f15 = sk[14] * c[2];
        const float f16 = sk[15] * c[3];
        const float f17 = sk[16] * c[3];
        const float f18 = sk[17] * c[15];
        const float f19 = sk[18] * c[15];
        const float f20 = sk[19] * c[16] * c[5];
        const float f21 = sk[20] * c[18];
        const float f22 = sk[21] * c[18];
        const float f23 = sk[22] * c[0]  * c[3];
        const float f24 = sk[23] * c[18] * c[0];
        const float f25 = sk[24] * c[19];

        float dy[20];
        dy[0]  = -f1 - f10 - f14 - f23 - f24 + f2 + f3 + f9 + f11 + f12 + f22 + f25;
        dy[1]  = -f2 - f3 - f9 - f12 + f1 + f21;
        dy[2]  = -f15 + f1 + f17 + f19 + f22;
        dy[3]  = -f2 - f16 - f17 - f23 + f15;
        dy[4]  = -f3 + 2.0f * f4 + f6 + f7 + f13 + f20;
        dy[5]  = -f6 - f8 - f14 - f20 + f3 + 2.0f * f18;
        dy[6]  = -f4 - f5 - f6 + f13;
        dy[7]  =  f4 + f5 + f6 + f7;
        dy[8]  = -f7 - f8;
        dy[9]  = -f12 + f7 + f9;
        dy[10] = -f9 - f10 + f8 + f11;
        dy[11] =  f9;
        dy[12] = -f11 + f10;
        dy[13] = -f13 + f12;
        dy[14] =  f14;
        dy[15] = -f18 - f19 + f16;
        dy[16] = -f20;
        dy[17] =  f20;
        dy[18] = -f21 - f22 - f24 + f23 + f25;
        dy[19] = -f25 + f24;

#pragma unroll
        for (int s = 0; s < 20; ++s) lds[t * PAD + s] = dy[s];
    }
    __syncthreads();

    // Dense store phase: block covers 256*20 floats = 1280 float4s.
    // Each output float4 J holds floats of exactly one column (20 % 4 == 0):
    // column q = J/5, starting species r = 4*(J%5) -> contiguous in LDS.
    float4* outv = (float4*)out;
    const int blockBaseF4 = blockIdx.x * 1280;
    const int nF4 = nvalid * 5;
#pragma unroll
    for (int i = 0; i < 5; ++i) {
        const int J = i * 256 + t;
        if (J < nF4) {
            const int q = J / 5;
            const int r = 4 * (J % 5);
            const float* p = &lds[q * PAD + r];
            outv[blockBaseF4 + J] = make_float4(p[0], p[1], p[2], p[3]);
        }
    }
}

extern "C" void kernel_launch(void* const* d_in, const int* in_sizes, int n_in,
                              void* d_out, int out_size, void* d_ws, size_t ws_size,
                              hipStream_t stream) {
    // d_in[0] = t (unused), d_in[1] = conc_in [20, B], d_in[2] = k [25]
    const float* conc = (const float*)d_in[1];
    const float* k    = (const float*)d_in[2];
    float* out        = (float*)d_out;

    const int block = 256;
    const int grid  = (B_TOTAL + block - 1) / block;
    pollu_kernel<<<grid, block, 0, stream>>>(conc, k, out);
}